// Round 16
// baseline (152.425 us; speedup 1.0000x reference)
//
#include <hip/hip_runtime.h>
#include <hip/hip_bf16.h>
#include <stdint.h>
#include <math.h>

#define HEADS 12
#define HD 64
#define NB 4
#define NSEQ 2048
#define DIM 768
#define MROWS (NB*NSEQ)          // 8192
#define QKV_OUT (3*DIM)          // 2304
#define QSCALE (0.03608439182435161f * 1.4426950408889634f)  // 768^-0.5 * log2(e)

typedef __bf16 bf16;
typedef __attribute__((ext_vector_type(8))) __bf16 bf16x8;
typedef __attribute__((ext_vector_type(4))) __bf16 bf16x4;
typedef __attribute__((ext_vector_type(4))) float f32x4;
typedef __attribute__((ext_vector_type(16))) float f32x16;
typedef unsigned int uint;

typedef __attribute__((address_space(1))) void gvoid_t;
typedef __attribute__((address_space(3))) void lvoid_t;
#define GLOAD_LDS16(src, dst) \
  __builtin_amdgcn_global_load_lds((gvoid_t*)(src), (lvoid_t*)(dst), 16, 0, 0)

// bare v_exp_f32 (2^x): avoids __ocml_exp2_f32's safe path.
__device__ __forceinline__ float fast_exp2(float x) {
  float r; asm("v_exp_f32 %0, %1" : "=v"(r) : "v"(x)); return r;
}
__device__ __forceinline__ uint cvtpk_bf16(float a, float b) {
  uint r; asm("v_cvt_pk_bf16_f32 %0, %1, %2" : "=v"(r) : "v"(a), "v"(b)); return r;
}
// NOTE: operands must hold DISTINCT values (distinct SSA) — identical inputs can
// coalesce to one register and break the swap (R6 post-mortem).
__device__ __forceinline__ void plswap(uint &a, uint &b) {
  asm("v_permlane32_swap_b32 %0, %1" : "+v"(a), "+v"(b));
}

// ---------------- fused f32 -> bf16 convert for x, w_qkv, w_out ----------------
__global__ void k_cvt3(const float* __restrict__ x, const float* __restrict__ wqkv,
                       const float* __restrict__ wout,
                       bf16* __restrict__ xb, bf16* __restrict__ wqkvb,
                       bf16* __restrict__ woutb) {
  const int n0 = MROWS * DIM / 4, n1 = QKV_OUT * DIM / 4, n2 = DIM * DIM / 4;
  int i = blockIdx.x * blockDim.x + threadIdx.x;
  const float* src; bf16* dst;
  if (i < n0)           { src = x;    dst = xb; }
  else if (i < n0 + n1) { src = wqkv; dst = wqkvb; i -= n0; }
  else if (i < n0 + n1 + n2) { src = wout; dst = woutb; i -= n0 + n1; }
  else return;
  const f32x4 v = ((const f32x4*)src)[i];
  bf16x4 o;
#pragma unroll
  for (int j = 0; j < 4; ++j) o[j] = (bf16)v[j];
  ((bf16x4*)dst)[i] = o;
}

// ---------------- LDS staging (GEMM): 8192 B tile, XOR-swizzled via global src ----
template<int ROWBYTES>
__device__ __forceinline__ void stage_swz(const bf16* g, int grow0, int gstride,
                                          int gcol0, char* ldsbuf) {
  constexpr int CPR = ROWBYTES / 16;
  const int t = threadIdx.x;
  const int wid = t >> 6;
#pragma unroll
  for (int call = 0; call < 2; ++call) {
    const int o = call * 4096 + t * 16;
    const int r = o / ROWBYTES;
    const int c = (o % ROWBYTES) / 16;
    const int cs = c ^ (r & (CPR - 1));
    const bf16* src = g + (long)(grow0 + r) * gstride + gcol0 + cs * 8;
    char* dst = ldsbuf + call * 4096 + wid * 1024;
    GLOAD_LDS16(src, dst);
  }
}

template<int ROWBYTES>
__device__ __forceinline__ bf16x8 frag_ld(const char* buf, int row, int chunk) {
  constexpr int CPR = ROWBYTES / 16;
  const int cs = chunk ^ (row & (CPR - 1));
  return *(const bf16x8*)(buf + row * ROWBYTES + cs * 16);
}

// P^T regs -> two bf16x8 B-frags (kv 0..15, 16..31) via cvt_pk + permlane32_swap
__device__ __forceinline__ void build_pfrags(const f32x16 &p, bf16x8 *f) {
  union { uint u[4]; bf16x8 v; } A, B;
  uint a0 = cvtpk_bf16(p[0], p[1]),  b0 = cvtpk_bf16(p[4], p[5]);   plswap(a0, b0);
  uint a1 = cvtpk_bf16(p[2], p[3]),  b1 = cvtpk_bf16(p[6], p[7]);   plswap(a1, b1);
  A.u[0] = a0; A.u[1] = a1; A.u[2] = b0; A.u[3] = b1;
  uint a2 = cvtpk_bf16(p[8], p[9]),  b2 = cvtpk_bf16(p[12], p[13]); plswap(a2, b2);
  uint a3 = cvtpk_bf16(p[10], p[11]), b3 = cvtpk_bf16(p[14], p[15]); plswap(a3, b3);
  B.u[0] = a2; B.u[1] = a3; B.u[2] = b2; B.u[3] = b3;
  f[0] = A.v; f[1] = B.v;
}

// ---------------- GEMM core (32x32x16): C[128x128] tile, A[M,K] rm, B[N,K] rm --------
__device__ __forceinline__ void gemm_core(const bf16* __restrict__ A, const bf16* __restrict__ Bm,
                                          int m0, int n0, f32x16 acc[2][2], char* lds) {
  const int t = threadIdx.x;
  const int lane = t & 63, wid = t >> 6;
  const int l31 = lane & 31, hi = lane >> 5;
  const int wm = wid >> 1, wn = wid & 1;
#pragma unroll
  for (int i = 0; i < 2; ++i)
#pragma unroll
    for (int j = 0; j < 2; ++j)
#pragma unroll
      for (int r = 0; r < 16; ++r) acc[i][j][r] = 0.f;

  stage_swz<64>(A, m0, DIM, 0, lds);
  stage_swz<64>(Bm, n0, DIM, 0, lds + 16384);
  __syncthreads();
  int cur = 0;
  const int NT = DIM / 32;   // 24
  for (int kt = 0; kt < NT; ++kt) {
    char* Acur = lds + cur * 8192;
    char* Bcur = lds + 16384 + cur * 8192;
    if (kt + 1 < NT) {
      stage_swz<64>(A, m0, DIM, (kt + 1) * 32, lds + (cur ^ 1) * 8192);
      stage_swz<64>(Bm, n0, DIM, (kt + 1) * 32, lds + 16384 + (cur ^ 1) * 8192);
    }
    bf16x8 af[2][2], bfr[2][2];   // [tile][k-half]
#pragma unroll
    for (int i = 0; i < 2; ++i)
#pragma unroll
      for (int h = 0; h < 2; ++h) {
        af[i][h]  = frag_ld<64>(Acur, wm * 64 + i * 32 + l31, h * 2 + hi);
        bfr[i][h] = frag_ld<64>(Bcur, wn * 64 + i * 32 + l31, h * 2 + hi);
      }
#pragma unroll
    for (int h = 0; h < 2; ++h)
#pragma unroll
      for (int i = 0; i < 2; ++i)
#pragma unroll
        for (int j = 0; j < 2; ++j)
          acc[i][j] = __builtin_amdgcn_mfma_f32_32x32x16_bf16(af[i][h], bfr[j][h], acc[i][j], 0, 0, 0);
    __syncthreads();
    cur ^= 1;
  }
}

// ---------------- QKV GEMM -------------------------------------------------------------
__global__ void __launch_bounds__(256) k_qkv_gemm(const bf16* __restrict__ xb,
                                                  const bf16* __restrict__ wb,
                                                  const float* __restrict__ bqkv,
                                                  bf16* __restrict__ qb,
                                                  bf16* __restrict__ kb,
                                                  bf16* __restrict__ vtb) {
  __shared__ alignas(128) char lds[32768];
  const int m0 = blockIdx.x * 128;
  const int n0 = blockIdx.y * 128;
  const int region = n0 / DIM;                 // 0=q,1=k,2=v (uniform per block)
  const int t = threadIdx.x;
  const int lane = t & 63, wid = t >> 6;
  const int l31 = lane & 31, hi = lane >> 5;
  const int wm = wid >> 1, wn = wid & 1;
  f32x16 acc[2][2];

  if (region < 2) {
    gemm_core(wb, xb, n0, m0, acc, lds);       // acc: row=o-features, col=x-rows
    bf16* dst0 = (region == 0) ? qb : kb;
#pragma unroll
    for (int i = 0; i < 2; ++i)
#pragma unroll
      for (int q = 0; q < 4; ++q) {
        const int o = n0 + wm * 64 + i * 32 + 8 * q + 4 * hi;  // feature (4-aligned)
        const f32x4 b4 = *(const f32x4*)(bqkv + o);
        const int oc = o - region * DIM;
        const int h = oc >> 6, d = oc & 63;
#pragma unroll
        for (int j = 0; j < 2; ++j) {
          const int mb = m0 + wn * 64 + j * 32 + l31;
          const int bb = mb >> 11, nn = mb & 2047;
          bf16x4 pk;
#pragma unroll
          for (int s = 0; s < 4; ++s) {
            float v = acc[i][j][4 * q + s] + b4[s];
            if (region == 0) v *= QSCALE;
            pk[s] = (bf16)v;
          }
          *(bf16x4*)(dst0 + ((long)((bb * HEADS + h) * NSEQ + nn)) * HD + d) = pk;
        }
      }
  } else {
    gemm_core(xb, wb, m0, n0, acc, lds);       // acc: row=x-rows, col=o-features
#pragma unroll
    for (int j = 0; j < 2; ++j) {
      const int o = n0 + wn * 64 + j * 32 + l31;
      const float bias = bqkv[o];
      const int oc = o - 2 * DIM;
      const int h = oc >> 6, d = oc & 63;
#pragma unroll
      for (int i = 0; i < 2; ++i)
#pragma unroll
        for (int q = 0; q < 4; ++q) {
          const int rowb = m0 + wm * 64 + i * 32 + 8 * q + 4 * hi;  // x-row (4-aligned)
          const int bb = rowb >> 11, nn = rowb & 2047;
          bf16x4 pk;
#pragma unroll
          for (int s = 0; s < 4; ++s) pk[s] = (bf16)(acc[i][j][4 * q + s] + bias);
          *(bf16x4*)(vtb + ((long)((bb * HEADS + h) * HD + d)) * NSEQ + nn) = pk;
        }
    }
  }
}

// ---------------- Flash attention: QBLK=64/wave, 2-wave blocks, Kx3+Vx2 = 40 KB -------
// grid(48 bh, 16 qtiles), 128 threads. R11 structure (pf-carry, spill-free) with LDS
// diet 48->40 KB -> 4 blocks/CU = 8 waves/CU (R11 had 6) + R14 stagger. Each wave owns
// 64 q-rows: every K/V frag read feeds 2 MFMA -> LDS pipe traffic HALVES vs QBLK=32
// (the per-CU LDS issue was ~45% of the R13/R14 wall). Max-free softmax (see R7).
// LDS: K slots {0,8192,16384}, V slots {24576,32768}.
__global__ void __launch_bounds__(128, 2) k_attn(const bf16* __restrict__ qb,
                                                 const bf16* __restrict__ kb,
                                                 const bf16* __restrict__ vtb,
                                                 bf16* __restrict__ ob) {
  __shared__ alignas(128) char lds[40960];
  char* ldsc = lds;
  const int bh = blockIdx.x;
  const int qt = blockIdx.y;
  const int t = threadIdx.x;
  const int lane = t & 63, wid = t >> 6;      // wid in {0,1}
  const int l31 = lane & 31, hi = lane >> 5;
  const bf16* qg = qb + (long)bh * NSEQ * HD;
  const bf16* kg = kb + (long)bh * NSEQ * HD;
  const bf16* vg = vtb + (long)bh * HD * NSEQ;
  const int q0w = qt * 128 + wid * 64;

  // Q B-frags for both halves: col q = h*32 + l31, d = ks*16 + hi*8
  bf16x8 bq[4][2];
#pragma unroll
  for (int ks = 0; ks < 4; ++ks)
#pragma unroll
    for (int h = 0; h < 2; ++h)
      bq[ks][h] = *(const bf16x8*)(qg + (long)(q0w + h * 32 + l31) * HD + ks * 16 + hi * 8);

  // per-lane swizzled LDS read base (rows 128 B, 8 chunks; same for K and V^T tiles)
  const int rbase = l31 * 128 + (((hi ^ l31) & 7) << 4);

  // staging: 8 KB tile = 4 chunks x 2 KB; cs = (t&7)^((t>>3)&7) is chunk-independent
  const int cs = (t & 7) ^ ((t >> 3) & 7);
  const bf16* kbase = kg + (t >> 3) * 64 + cs * 8;           // + c*1024 + j*4096
  const bf16* vbase = vg + (long)(t >> 3) * NSEQ + cs * 8;   // + c*32768 + j*64
  const int dofs = wid << 10;

  auto stage_k = [&](int j, int slot) {
#pragma unroll
    for (int c = 0; c < 4; ++c)
      GLOAD_LDS16(kbase + j * 4096 + c * 1024, ldsc + slot * 8192 + c * 2048 + dofs);
  };
  auto stage_v = [&](int j, int slot) {
#pragma unroll
    for (int c = 0; c < 4; ++c)
      GLOAD_LDS16(vbase + (long)j * 64 + (long)c * 32768,
                  ldsc + 24576 + slot * 8192 + c * 2048 + dofs);
  };

  f32x16 ot00, ot01, ot10, ot11;
#pragma unroll
  for (int r = 0; r < 16; ++r) { ot00[r] = 0.f; ot01[r] = 0.f; ot10[r] = 0.f; ot11[r] = 0.f; }
  float l0 = 0.f, l1 = 0.f;
  bf16x8 pf0[4], pf1[4];

  // QK^T: 8 ds_read K -> 16 MFMA (2 q-halves share each A-frag)
  auto qkt = [&](int kslot, f32x16 &S00, f32x16 &S01, f32x16 &S10, f32x16 &S11) {
#pragma unroll
    for (int r = 0; r < 16; ++r) { S00[r] = 0.f; S01[r] = 0.f; S10[r] = 0.f; S11[r] = 0.f; }
    __builtin_amdgcn_s_setprio(1);
#pragma unroll
    for (int ks = 0; ks < 4; ++ks) {
      const int a = (rbase ^ (ks << 5)) + kslot * 8192;
      const bf16x8 ak0 = *(const bf16x8*)(ldsc + a);
      const bf16x8 ak1 = *(const bf16x8*)(ldsc + a + 4096);
      S00 = __builtin_amdgcn_mfma_f32_32x32x16_bf16(ak0, bq[ks][0], S00, 0, 0, 0);
      S10 = __builtin_amdgcn_mfma_f32_32x32x16_bf16(ak0, bq[ks][1], S10, 0, 0, 0);
      S01 = __builtin_amdgcn_mfma_f32_32x32x16_bf16(ak1, bq[ks][0], S01, 0, 0, 0);
      S11 = __builtin_amdgcn_mfma_f32_32x32x16_bf16(ak1, bq[ks][1], S11, 0, 0, 0);
    }
    __builtin_amdgcn_s_setprio(0);
  };

  // PV: 8 ds_read V -> 16 MFMA (2 q-halves share each A-frag)
  auto pv = [&](int vslot) {
    __builtin_amdgcn_s_setprio(1);
#pragma unroll
    for (int s = 0; s < 4; ++s) {
      const int a = (rbase ^ (s << 5)) + 24576 + vslot * 8192;
      const bf16x8 av0 = *(const bf16x8*)(ldsc + a);
      const bf16x8 av1 = *(const bf16x8*)(ldsc + a + 4096);
      ot00 = __builtin_amdgcn_mfma_f32_32x32x16_bf16(av0, pf0[s], ot00, 0, 0, 0);
      ot10 = __builtin_amdgcn_mfma_f32_32x32x16_bf16(av0, pf1[s], ot10, 0, 0, 0);
      ot01 = __builtin_amdgcn_mfma_f32_32x32x16_bf16(av1, pf0[s], ot01, 0, 0, 0);
      ot11 = __builtin_amdgcn_mfma_f32_32x32x16_bf16(av1, pf1[s], ot11, 0, 0, 0);
    }
    __builtin_amdgcn_s_setprio(0);
  };

  auto exppack = [&](f32x16 &S00, f32x16 &S01, f32x16 &S10, f32x16 &S11) {
    float a0 = 0.f, a1 = 0.f, b0 = 0.f, b1 = 0.f;
#pragma unroll
    for (int r = 0; r < 16; ++r) {
      S00[r] = fast_exp2(S00[r]); a0 += S00[r];
      S01[r] = fast_exp2(S01[r]); a1 += S01[r];
      S10[r] = fast_exp2(S10[r]); b0 += S10[r];
      S11[r] = fast_exp2(S11[r]); b1 += S11[r];
    }
    l0 += a0 + a1;
    l1 += b0 + b1;
    build_pfrags(S00, &pf0[0]);
    build_pfrags(S01, &pf0[2]);
    build_pfrags(S10, &pf1[0]);
    build_pfrags(S11, &pf1[2]);
  };

  // prologue: K(0); drain; S(0); stage K(1),V(0); pack P(0)
  stage_k(0, 0);
  asm volatile("s_waitcnt vmcnt(0)" ::: "memory");
  __builtin_amdgcn_s_barrier();
  asm volatile("" ::: "memory");
  {
    f32x16 S00, S01, S10, S11;
    qkt(0, S00, S01, S10, S11);
    stage_k(1, 1);
    stage_v(0, 0);
    exppack(S00, S01, S10, S11);
  }

  for (int tt = 0; tt < 31; ++tt) {
    asm volatile("s_waitcnt vmcnt(0)" ::: "memory");  // K(t+1),V(t) issued last iter
    __builtin_amdgcn_s_barrier();
    asm volatile("" ::: "memory");
    stage_k(tt + 2 < 32 ? tt + 2 : 31, (tt + 2) % 3);
    stage_v(tt + 1, (tt + 1) & 1);
    f32x16 S00, S01, S10, S11;
    if (wid & 1) {
      qkt((tt + 1) % 3, S00, S01, S10, S11);          // S(t+1)
      pv(tt & 1);                                     // PV(t)
    } else {
      pv(tt & 1);                                     // stagger: PV first on even waves
      qkt((tt + 1) % 3, S00, S01, S10, S11);
    }
    exppack(S00, S01, S10, S11);                      // P(t+1) -> pf
  }
  // final PV(31): V(31) in slot 31&1 = 1
  asm volatile("s_waitcnt vmcnt(0)" ::: "memory");
  __builtin_amdgcn_s_barrier();
  asm volatile("" ::: "memory");
  pv(1);

  // epilogue: combine l halves, O^T/l, transpose via wave-private LDS strip
  l0 += __shfl_xor(l0, 32);
  l1 += __shfl_xor(l1, 32);
  const float i0 = 1.f / l0, i1 = 1.f / l1;
#pragma unroll
  for (int r = 0; r < 16; ++r) { ot00[r] *= i0; ot01[r] *= i0; ot10[r] *= i1; ot11[r] *= i1; }
  char* tw = lds + wid * 8704;             // 64 rows x 136 B per wave (K region; reads done)
#pragma unroll
  for (int g = 0; g < 4; ++g) {
    const int d0 = 8 * g + 4 * hi;
    uint2 w0, w1;
    w0.x = cvtpk_bf16(ot00[4 * g], ot00[4 * g + 1]);
    w0.y = cvtpk_bf16(ot00[4 * g + 2], ot00[4 * g + 3]);
    w1.x = cvtpk_bf16(ot01[4 * g], ot01[4 * g + 1]);
    w1.y = cvtpk_bf16(ot01[4 * g + 2], ot01[4 * g + 3]);
    *(uint2*)(tw + l31 * 136 + d0 * 2) = w0;
    *(uint2*)(tw + l31 * 136 + (32 + d0) * 2) = w1;
    uint2 x0, x1;
    x0.x = cvtpk_bf16(ot10[4 * g], ot10[4 * g + 1]);
    x0.y = cvtpk_bf16(ot10[4 * g + 2], ot10[4 * g + 3]);
    x1.x = cvtpk_bf16(ot11[4 * g], ot11[4 * g + 1]);
    x1.y = cvtpk_bf16(ot11[4 * g + 2], ot11[4 * g + 3]);
    *(uint2*)(tw + (32 + l31) * 136 + d0 * 2) = x0;
    *(uint2*)(tw + (32 + l31) * 136 + (32 + d0) * 2) = x1;
  }
  const int b_ = bh / HEADS, h_ = bh - b_ * HEADS;
#pragma unroll
  for (int pass = 0; pass < 8; ++pass) {
    const int row = pass * 8 + (lane >> 3);
    const bf16x8 vv = *(const bf16x8*)(tw + row * 136 + (lane & 7) * 16);
    *(bf16x8*)(ob + ((long)(b_ * NSEQ + q0w + row)) * DIM + h_ * 64 + (lane & 7) * 8) = vv;
  }
}

// ---------------- Output GEMM (swapped orientation): f32x4 stores ---------------------
__global__ void __launch_bounds__(256) k_out_gemm(const bf16* __restrict__ ab,
                                                  const bf16* __restrict__ wob,
                                                  const float* __restrict__ bout,
                                                  float* __restrict__ out) {
  __shared__ alignas(128) char lds[32768];
  const int m0 = blockIdx.x * 128;
  const int n0 = blockIdx.y * 128;
  f32x16 acc[2][2];
  gemm_core(wob, ab, n0, m0, acc, lds);        // acc: row=o-features, col=m-rows

  const int t = threadIdx.x;
  const int lane = t & 63, wid = t >> 6;
  const int l31 = lane & 31, hi = lane >> 5;
  const int wm = wid >> 1, wn = wid & 1;
#pragma unroll
  for (int i = 0; i < 2; ++i)
#pragma unroll
    for (int q = 0; q < 4; ++q) {
      const int o = n0 + wm * 64 + i * 32 + 8 * q + 4 * hi;    // feature (4-aligned)
      const f32x4 b4 = *(const f32x4*)(bout + o);
#pragma unroll
      for (int j = 0; j < 2; ++j) {
        const int mb = m0 + wn * 64 + j * 32 + l31;
        f32x4 v;
#pragma unroll
        for (int s = 0; s < 4; ++s) v[s] = acc[i][j][4 * q + s] + b4[s];
        *(f32x4*)(out + (long)mb * DIM + o) = v;
      }
    }
}

// ---------------- launch --------------------------------------------------------------
extern "C" void kernel_launch(void* const* d_in, const int* in_sizes, int n_in,
                              void* d_out, int out_size, void* d_ws, size_t ws_size,
                              hipStream_t stream) {
  const float* x    = (const float*)d_in[0];
  const float* wqkv = (const float*)d_in[1];
  const float* bqkv = (const float*)d_in[2];
  const float* wout = (const float*)d_in[3];
  const float* bout = (const float*)d_in[4];
  float* out = (float*)d_out;
  char* ws = (char*)d_ws;

  bf16* xb    = (bf16*)(ws);                 // 8192*768*2  = 12582912
  bf16* wqkvb = (bf16*)(ws + 12582912);      // 2304*768*2  =  3538944
  bf16* woutb = (bf16*)(ws + 16121856);      // 768*768*2   =  1179648
  bf16* qb    = (bf16*)(ws + 17301504);      // 12582912  [b,h,n,d] (pre-scaled, exp2 domain)
  bf16* kb    = (bf16*)(ws + 29884416);      // 12582912  [b,h,n,d]
  bf16* vtb   = (bf16*)(ws + 42467328);      // 12582912  [b,h,d,n]
  bf16* ab    = (bf16*)(ws + 55050240);      // 12582912  [b*n, 768]

  const int ncvt4 = MROWS * DIM / 4 + QKV_OUT * DIM / 4 + DIM * DIM / 4;
  k_cvt3<<<(ncvt4 + 255) / 256, 256, 0, stream>>>(x, wqkv, wout, xb, wqkvb, woutb);

  k_qkv_gemm<<<dim3(MROWS / 128, QKV_OUT / 128), 256, 0, stream>>>(xb, wqkvb, bqkv, qb, kb, vtb);
  k_attn<<<dim3(NB * HEADS, NSEQ / 128), 128, 0, stream>>>(qb, kb, vtb, ab);
  k_out_gemm<<<dim3(MROWS / 128, DIM / 128), 256, 0, stream>>>(ab, woutb, bout, out);
}

// Round 17
// 139.877 us; speedup vs baseline: 1.0897x; 1.0897x over previous
//
#include <hip/hip_runtime.h>
#include <hip/hip_bf16.h>
#include <stdint.h>
#include <math.h>

#define HEADS 12
#define HD 64
#define NB 4
#define NSEQ 2048
#define DIM 768
#define MROWS (NB*NSEQ)          // 8192
#define QKV_OUT (3*DIM)          // 2304
#define QSCALE (0.03608439182435161f * 1.4426950408889634f)  // 768^-0.5 * log2(e)

typedef __bf16 bf16;
typedef __attribute__((ext_vector_type(8))) __bf16 bf16x8;
typedef __attribute__((ext_vector_type(4))) __bf16 bf16x4;
typedef __attribute__((ext_vector_type(4))) float f32x4;
typedef __attribute__((ext_vector_type(16))) float f32x16;
typedef unsigned int uint;

typedef __attribute__((address_space(1))) void gvoid_t;
typedef __attribute__((address_space(3))) void lvoid_t;
#define GLOAD_LDS16(src, dst) \
  __builtin_amdgcn_global_load_lds((gvoid_t*)(src), (lvoid_t*)(dst), 16, 0, 0)

// bare v_exp_f32 (2^x): avoids __ocml_exp2_f32's safe path.
__device__ __forceinline__ float fast_exp2(float x) {
  float r; asm("v_exp_f32 %0, %1" : "=v"(r) : "v"(x)); return r;
}
__device__ __forceinline__ uint cvtpk_bf16(float a, float b) {
  uint r; asm("v_cvt_pk_bf16_f32 %0, %1, %2" : "=v"(r) : "v"(a), "v"(b)); return r;
}
// NOTE: operands must hold DISTINCT values (distinct SSA) — identical inputs can
// coalesce to one register and break the swap (R6 post-mortem).
__device__ __forceinline__ void plswap(uint &a, uint &b) {
  asm("v_permlane32_swap_b32 %0, %1" : "+v"(a), "+v"(b));
}

// ---------------- fused f32 -> bf16 convert for x, w_qkv, w_out ----------------
__global__ void k_cvt3(const float* __restrict__ x, const float* __restrict__ wqkv,
                       const float* __restrict__ wout,
                       bf16* __restrict__ xb, bf16* __restrict__ wqkvb,
                       bf16* __restrict__ woutb) {
  const int n0 = MROWS * DIM / 4, n1 = QKV_OUT * DIM / 4, n2 = DIM * DIM / 4;
  int i = blockIdx.x * blockDim.x + threadIdx.x;
  const float* src; bf16* dst;
  if (i < n0)           { src = x;    dst = xb; }
  else if (i < n0 + n1) { src = wqkv; dst = wqkvb; i -= n0; }
  else if (i < n0 + n1 + n2) { src = wout; dst = woutb; i -= n0 + n1; }
  else return;
  const f32x4 v = ((const f32x4*)src)[i];
  bf16x4 o;
#pragma unroll
  for (int j = 0; j < 4; ++j) o[j] = (bf16)v[j];
  ((bf16x4*)dst)[i] = o;
}

// ---------------- LDS staging (GEMM): 8192 B tile, XOR-swizzled via global src ----
template<int ROWBYTES>
__device__ __forceinline__ void stage_swz(const bf16* g, int grow0, int gstride,
                                          int gcol0, char* ldsbuf) {
  constexpr int CPR = ROWBYTES / 16;
  const int t = threadIdx.x;
  const int wid = t >> 6;
#pragma unroll
  for (int call = 0; call < 2; ++call) {
    const int o = call * 4096 + t * 16;
    const int r = o / ROWBYTES;
    const int c = (o % ROWBYTES) / 16;
    const int cs = c ^ (r & (CPR - 1));
    const bf16* src = g + (long)(grow0 + r) * gstride + gcol0 + cs * 8;
    char* dst = ldsbuf + call * 4096 + wid * 1024;
    GLOAD_LDS16(src, dst);
  }
}

template<int ROWBYTES>
__device__ __forceinline__ bf16x8 frag_ld(const char* buf, int row, int chunk) {
  constexpr int CPR = ROWBYTES / 16;
  const int cs = chunk ^ (row & (CPR - 1));
  return *(const bf16x8*)(buf + row * ROWBYTES + cs * 16);
}

// P^T regs -> two bf16x8 B-frags (kv 0..15, 16..31) via cvt_pk + permlane32_swap
__device__ __forceinline__ void build_pfrags(const f32x16 &p, bf16x8 *f) {
  union { uint u[4]; bf16x8 v; } A, B;
  uint a0 = cvtpk_bf16(p[0], p[1]),  b0 = cvtpk_bf16(p[4], p[5]);   plswap(a0, b0);
  uint a1 = cvtpk_bf16(p[2], p[3]),  b1 = cvtpk_bf16(p[6], p[7]);   plswap(a1, b1);
  A.u[0] = a0; A.u[1] = a1; A.u[2] = b0; A.u[3] = b1;
  uint a2 = cvtpk_bf16(p[8], p[9]),  b2 = cvtpk_bf16(p[12], p[13]); plswap(a2, b2);
  uint a3 = cvtpk_bf16(p[10], p[11]), b3 = cvtpk_bf16(p[14], p[15]); plswap(a3, b3);
  B.u[0] = a2; B.u[1] = a3; B.u[2] = b2; B.u[3] = b3;
  f[0] = A.v; f[1] = B.v;
}

// ---------------- GEMM core (16x16x32, 3-slot counted-vmcnt pipeline) -----------------
// C[128x128] tile, A[M,K] rm, B[N,K] rm (B^T). 4 waves (2x2), 64x64/wave.
// Slots: A at {0,8192,16384}, B at 24576+{0,8192,16384} = 49152 B. Stage distance 2;
// iter top: vmcnt(4) retires tile t's loads (issued 2 iters ago, ~free) + raw barrier;
// tiles t+1, t+2 stay in flight across the barrier (T4). Clamped tail keeps counts
// uniform; vmcnt(0) after loop guards LDS-DMA vs workgroup teardown.
__device__ __forceinline__ void gemm_core(const bf16* __restrict__ A, const bf16* __restrict__ Bm,
                                          int m0, int n0, f32x4 acc[4][4], char* lds) {
  const int t = threadIdx.x;
  const int lane = t & 63, wid = t >> 6;
  const int lr = lane & 15, l4 = lane >> 4;
  const int wm = wid >> 1, wn = wid & 1;
#pragma unroll
  for (int i = 0; i < 4; ++i)
#pragma unroll
    for (int j = 0; j < 4; ++j) acc[i][j] = f32x4{0.f, 0.f, 0.f, 0.f};

  const int NT = DIM / 32;   // 24
  stage_swz<64>(A, m0, DIM, 0, lds);
  stage_swz<64>(Bm, n0, DIM, 0, lds + 24576);
  stage_swz<64>(A, m0, DIM, 32, lds + 8192);
  stage_swz<64>(Bm, n0, DIM, 32, lds + 24576 + 8192);
  for (int kt = 0; kt < NT; ++kt) {
    asm volatile("s_waitcnt vmcnt(4)" ::: "memory");   // retire tile kt's 4 loads
    __builtin_amdgcn_s_barrier();
    asm volatile("" ::: "memory");
    const int jn = (kt + 2 < NT) ? (kt + 2) : (NT - 1);
    const int snxt = (kt + 2) % 3;
    stage_swz<64>(A, m0, DIM, jn * 32, lds + snxt * 8192);
    stage_swz<64>(Bm, n0, DIM, jn * 32, lds + 24576 + snxt * 8192);
    char* Acur = lds + (kt % 3) * 8192;
    char* Bcur = lds + 24576 + (kt % 3) * 8192;
    bf16x8 af[4], bfr[4];
#pragma unroll
    for (int i = 0; i < 4; ++i) af[i] = frag_ld<64>(Acur, wm * 64 + i * 16 + lr, l4);
#pragma unroll
    for (int j = 0; j < 4; ++j) bfr[j] = frag_ld<64>(Bcur, wn * 64 + j * 16 + lr, l4);
#pragma unroll
    for (int i = 0; i < 4; ++i)
#pragma unroll
      for (int j = 0; j < 4; ++j)
        acc[i][j] = __builtin_amdgcn_mfma_f32_16x16x32_bf16(af[i], bfr[j], acc[i][j], 0, 0, 0);
  }
  asm volatile("s_waitcnt vmcnt(0)" ::: "memory");     // drain before LDS dealloc
}

// ---------------- QKV GEMM (R14 epilogues) ---------------------------------------------
__global__ void __launch_bounds__(256) k_qkv_gemm(const bf16* __restrict__ xb,
                                                  const bf16* __restrict__ wb,
                                                  const float* __restrict__ bqkv,
                                                  bf16* __restrict__ qb,
                                                  bf16* __restrict__ kb,
                                                  bf16* __restrict__ vtb) {
  __shared__ alignas(128) char lds[49152];
  const int m0 = blockIdx.x * 128;
  const int n0 = blockIdx.y * 128;
  const int region = n0 / DIM;                 // 0=q,1=k,2=v (uniform per block)
  const int t = threadIdx.x;
  const int lane = t & 63, wid = t >> 6;
  const int lr = lane & 15, l4 = lane >> 4;
  const int wm = wid >> 1, wn = wid & 1;
  f32x4 acc[4][4];

  if (region < 2) {
    gemm_core(wb, xb, n0, m0, acc, lds);       // acc: row=o-features, col=x-rows
    bf16* dst0 = (region == 0) ? qb : kb;
#pragma unroll
    for (int j = 0; j < 4; ++j) {
      const int mb = m0 + wn * 64 + j * 16 + lr;
      const int bb = mb >> 11, nn = mb & 2047;
#pragma unroll
      for (int i = 0; i < 4; ++i) {
        const int o = n0 + wm * 64 + i * 16 + l4 * 4;
        const f32x4 b4 = *(const f32x4*)(bqkv + o);
        const int oc = o - region * DIM;
        const int h = oc >> 6, d = oc & 63;
        bf16x4 pk;
#pragma unroll
        for (int r = 0; r < 4; ++r) {
          float v = acc[i][j][r] + b4[r];
          if (region == 0) v *= QSCALE;
          pk[r] = (bf16)v;
        }
        *(bf16x4*)(dst0 + ((long)((bb * HEADS + h) * NSEQ + nn)) * HD + d) = pk;
      }
    }
  } else {
    gemm_core(xb, wb, m0, n0, acc, lds);       // acc: row=x-rows, col=o-features
#pragma unroll
    for (int j = 0; j < 4; ++j) {
      const int o = n0 + wn * 64 + j * 16 + lr;
      const float bias = bqkv[o];
      const int oc = o - 2 * DIM;
      const int h = oc >> 6, d = oc & 63;
#pragma unroll
      for (int i = 0; i < 4; ++i) {
        const int mb = m0 + wm * 64 + i * 16 + l4 * 4;
        const int bb = mb >> 11, nn = mb & 2047;
        bf16x4 pk;
#pragma unroll
        for (int r = 0; r < 4; ++r) pk[r] = (bf16)(acc[i][j][r] + bias);
        *(bf16x4*)(vtb + ((long)((bb * HEADS + h) * HD + d)) * NSEQ + nn) = pk;
      }
    }
  }
}

// ---------------- Flash attention: KVBLK=128, 16 iters, pf-carry, wave-staggered ------
// (R14 config restored — best known: 70.7 us, VGPR 100, no spill.)
// grid(48 bh, 16 qtiles), 256 threads (4 waves x 32 q-rows).
// LDS: K slots {0,16384}, V slots {32768,49152} = 64 KB. Max-free softmax (see R7).
__global__ void __launch_bounds__(256, 2) k_attn(const bf16* __restrict__ qb,
                                                 const bf16* __restrict__ kb,
                                                 const bf16* __restrict__ vtb,
                                                 bf16* __restrict__ ob) {
  __shared__ alignas(128) char lds[65536];
  char* ldsc = lds;
  const int bh = blockIdx.x;
  const int qt = blockIdx.y;
  const int t = threadIdx.x;
  const int lane = t & 63, wid = t >> 6;
  const int l31 = lane & 31, hi = lane >> 5;
  const bf16* qg = qb + (long)bh * NSEQ * HD;
  const bf16* kg = kb + (long)bh * NSEQ * HD;
  const bf16* vg = vtb + (long)bh * HD * NSEQ;
  const int q0w = qt * 128 + wid * 32;

  bf16x8 bq[4];
#pragma unroll
  for (int ks = 0; ks < 4; ++ks)
    bq[ks] = *(const bf16x8*)(qg + (long)(q0w + l31) * HD + ks * 16 + hi * 8);

  const int rbase_k = l31 * 128 + ((hi ^ (l31 & 7)) << 4);
  const int rbase_v = l31 * 256 + ((hi ^ (l31 & 15)) << 4);

  const int cs_k = (t & 7) ^ ((t >> 3) & 7);
  const bf16* kbase = kg + (t >> 3) * 64 + cs_k * 8;
  const int cs_v = (t & 15) ^ ((t >> 4) & 15);
  const bf16* vbase = vg + (long)(t >> 4) * NSEQ + cs_v * 8;
  const int dofs = wid << 10;

  auto stage_k = [&](int j, int slot) {
#pragma unroll
    for (int c = 0; c < 4; ++c)
      GLOAD_LDS16(kbase + j * 8192 + c * 2048, ldsc + slot * 16384 + c * 4096 + dofs);
  };
  auto stage_v = [&](int j, int slot) {
#pragma unroll
    for (int c = 0; c < 4; ++c)
      GLOAD_LDS16(vbase + (long)j * 128 + (long)c * 32768,
                  ldsc + 32768 + slot * 16384 + c * 4096 + dofs);
  };

  f32x16 ot0, ot1;
#pragma unroll
  for (int r = 0; r < 16; ++r) { ot0[r] = 0.f; ot1[r] = 0.f; }
  float l_run = 0.f;
  bf16x8 pf[8];

  auto qkt128 = [&](int kslot, f32x16 S[4]) {
#pragma unroll
    for (int sub = 0; sub < 4; ++sub)
#pragma unroll
      for (int r = 0; r < 16; ++r) S[sub][r] = 0.f;
    __builtin_amdgcn_s_setprio(1);
#pragma unroll
    for (int ks = 0; ks < 4; ++ks) {
      const int a = kslot * 16384 + (rbase_k ^ (ks << 5));
#pragma unroll
      for (int sub = 0; sub < 4; ++sub) {
        const bf16x8 ak = *(const bf16x8*)(ldsc + a + sub * 4096);
        S[sub] = __builtin_amdgcn_mfma_f32_32x32x16_bf16(ak, bq[ks], S[sub], 0, 0, 0);
      }
    }
    __builtin_amdgcn_s_setprio(0);
  };

  auto exppack128 = [&](f32x16 S[4]) {
    float rs = 0.f;
#pragma unroll
    for (int sub = 0; sub < 4; ++sub) {
      float a = 0.f;
#pragma unroll
      for (int r = 0; r < 16; ++r) { S[sub][r] = fast_exp2(S[sub][r]); a += S[sub][r]; }
      rs += a;
      build_pfrags(S[sub], &pf[2 * sub]);
    }
    l_run += rs;
  };

  auto pv128 = [&](int vslot) {
    __builtin_amdgcn_s_setprio(1);
#pragma unroll
    for (int s = 0; s < 8; ++s) {
      const int a = 32768 + vslot * 16384 + (rbase_v ^ (s << 5));
      const bf16x8 av0 = *(const bf16x8*)(ldsc + a);
      ot0 = __builtin_amdgcn_mfma_f32_32x32x16_bf16(av0, pf[s], ot0, 0, 0, 0);
      const bf16x8 av1 = *(const bf16x8*)(ldsc + a + 8192);
      ot1 = __builtin_amdgcn_mfma_f32_32x32x16_bf16(av1, pf[s], ot1, 0, 0, 0);
    }
    __builtin_amdgcn_s_setprio(0);
  };

  stage_k(0, 0);
  asm volatile("s_waitcnt vmcnt(0)" ::: "memory");
  __builtin_amdgcn_s_barrier();
  asm volatile("" ::: "memory");
  {
    f32x16 S[4];
    qkt128(0, S);
    stage_k(1, 1);
    stage_v(0, 0);
    exppack128(S);
  }

  for (int tt = 0; tt < 15; ++tt) {
    asm volatile("s_waitcnt vmcnt(0)" ::: "memory");
    __builtin_amdgcn_s_barrier();
    asm volatile("" ::: "memory");
    stage_k(tt + 2 < 16 ? tt + 2 : 15, tt & 1);
    stage_v(tt + 1, (tt + 1) & 1);
    f32x16 S[4];
    if (wid & 1) {
      qkt128((tt + 1) & 1, S);
      pv128(tt & 1);
    } else {
      pv128(tt & 1);
      qkt128((tt + 1) & 1, S);
    }
    exppack128(S);
  }
  asm volatile("s_waitcnt vmcnt(0)" ::: "memory");
  __builtin_amdgcn_s_barrier();
  asm volatile("" ::: "memory");
  pv128(1);

  l_run += __shfl_xor(l_run, 32);
  const float inv = 1.f / l_run;
#pragma unroll
  for (int r = 0; r < 16; ++r) { ot0[r] *= inv; ot1[r] *= inv; }
  __builtin_amdgcn_s_barrier();
  char* tw = lds + wid * 4352;
#pragma unroll
  for (int g = 0; g < 4; ++g) {
    uint2 w0, w1;
    w0.x = cvtpk_bf16(ot0[4 * g], ot0[4 * g + 1]);
    w0.y = cvtpk_bf16(ot0[4 * g + 2], ot0[4 * g + 3]);
    w1.x = cvtpk_bf16(ot1[4 * g], ot1[4 * g + 1]);
    w1.y = cvtpk_bf16(ot1[4 * g + 2], ot1[4 * g + 3]);
    const int d0 = 8 * g + 4 * hi;
    *(uint2*)(tw + l31 * 136 + d0 * 2) = w0;
    *(uint2*)(tw + l31 * 136 + (32 + d0) * 2) = w1;
  }
  const int b_ = bh / HEADS, h_ = bh - b_ * HEADS;
#pragma unroll
  for (int pass = 0; pass < 4; ++pass) {
    const int row = pass * 8 + (lane >> 3);
    const bf16x8 vv = *(const bf16x8*)(tw + row * 136 + (lane & 7) * 16);
    *(bf16x8*)(ob + ((long)(b_ * NSEQ + q0w + row)) * DIM + h_ * 64 + (lane & 7) * 8) = vv;
  }
}

// ---------------- Output GEMM (swapped orientation): f32x4 stores ---------------------
__global__ void __launch_bounds__(256) k_out_gemm(const bf16* __restrict__ ab,
                                                  const bf16* __restrict__ wob,
                                                  const float* __restrict__ bout,
                                                  float* __restrict__ out) {
  __shared__ alignas(128) char lds[49152];
  const int m0 = blockIdx.x * 128;
  const int n0 = blockIdx.y * 128;
  f32x4 acc[4][4];
  gemm_core(wob, ab, n0, m0, acc, lds);        // acc: row=o-features, col=m-rows

  const int t = threadIdx.x;
  const int lane = t & 63, wid = t >> 6;
  const int lr = lane & 15, l4 = lane >> 4;
  const int wm = wid >> 1, wn = wid & 1;
#pragma unroll
  for (int j = 0; j < 4; ++j) {
    const int mb = m0 + wn * 64 + j * 16 + lr;
#pragma unroll
    for (int i = 0; i < 4; ++i) {
      const int o = n0 + wm * 64 + i * 16 + l4 * 4;
      const f32x4 v = acc[i][j] + *(const f32x4*)(bout + o);
      *(f32x4*)(out + (long)mb * DIM + o) = v;
    }
  }
}

// ---------------- launch --------------------------------------------------------------
extern "C" void kernel_launch(void* const* d_in, const int* in_sizes, int n_in,
                              void* d_out, int out_size, void* d_ws, size_t ws_size,
                              hipStream_t stream) {
  const float* x    = (const float*)d_in[0];
  const float* wqkv = (const float*)d_in[1];
  const float* bqkv = (const float*)d_in[2];
  const float* wout = (const float*)d_in[3];
  const float* bout = (const float*)d_in[4];
  float* out = (float*)d_out;
  char* ws = (char*)d_ws;

  bf16* xb    = (bf16*)(ws);                 // 8192*768*2  = 12582912
  bf16* wqkvb = (bf16*)(ws + 12582912);      // 2304*768*2  =  3538944
  bf16* woutb = (bf16*)(ws + 16121856);      // 768*768*2   =  1179648
  bf16* qb    = (bf16*)(ws + 17301504);      // 12582912  [b,h,n,d] (pre-scaled, exp2 domain)
  bf16* kb    = (bf16*)(ws + 29884416);      // 12582912  [b,h,n,d]
  bf16* vtb   = (bf16*)(ws + 42467328);      // 12582912  [b,h,d,n]
  bf16* ab    = (bf16*)(ws + 55050240);      // 12582912  [b*n, 768]

  const int ncvt4 = MROWS * DIM / 4 + QKV_OUT * DIM / 4 + DIM * DIM / 4;
  k_cvt3<<<(ncvt4 + 255) / 256, 256, 0, stream>>>(x, wqkv, wout, xb, wqkvb, woutb);

  k_qkv_gemm<<<dim3(MROWS / 128, QKV_OUT / 128), 256, 0, stream>>>(xb, wqkvb, bqkv, qb, kb, vtb);
  k_attn<<<dim3(NB * HEADS, NSEQ / 128), 256, 0, stream>>>(qb, kb, vtb, ab);
  k_out_gemm<<<dim3(MROWS / 128, DIM / 128), 256, 0, stream>>>(ab, woutb, bout, out);
}